// Round 15
// baseline (432.259 us; speedup 1.0000x reference)
//
#include <hip/hip_runtime.h>

// ---------------- problem constants ----------------
#define VOCAB 18
#define EMB   200
#define HID   200
#define G4    800           // 4*HID
#define SEQ   128
#define BATCH 2048
#define MB    8             // batch rows per block
#define NT    56            // N tiles: 50 gate (j-blocked) + 2 logit + 4 zero
#define KS    7             // K steps of 32 -> 224 padded K
                            // k<200: W_hh | k=200: logit bias | k=201+v: tbl[v]
#define TPB   256           // 4 waves -> 1 wave/SIMD -> 512-reg budget
#define TPW   14            // tiles per wave (56/4) -> 392 pinned AGPRs
#define SV    (SEQ*VOCAB)   // 2304
#define LOGITS_N ((size_t)BATCH*SEQ*VOCAB)

typedef short s16x8 __attribute__((ext_vector_type(8)));
typedef float f32x4 __attribute__((ext_vector_type(4)));

__device__ __forceinline__ unsigned short f2bf(float f) {
  unsigned int u = __float_as_uint(f);
  u += 0x7FFFu + ((u >> 16) & 1u);            // RNE; no NaNs in this problem
  return (unsigned short)(u >> 16);
}
__device__ __forceinline__ float sigm(float x) {
  float e = __builtin_amdgcn_exp2f(x * 1.4426950408889634f);
  return e * __builtin_amdgcn_rcpf(e + 1.0f);
}
__device__ __forceinline__ float tanhq(float x) {
  float e = __builtin_amdgcn_exp2f(x * 2.8853900817779268f); // exp2(2x*log2e)
  return 1.0f - 2.0f * __builtin_amdgcn_rcpf(e + 1.0f);
}

// one-hot/bias slot in hA for B[k][col c]: s=6 block (k in [192,224)).
// element = (384 + ((k>>3)&3)*16 + c)*8 + (k&7)   [R7-verified formula]
__device__ __forceinline__ int oh_elem(int c, int k) {
  return (384 + ((k >> 3) & 3) * 16 + c) * 8 + (k & 7);
}

// ---------------- prep 1: token table (gate-major cols, bf16 18x800) ------
// tbl[v][colg] = (v!=0)*dot(E[v], W_ih[colg]) + b_ih[colg] + b_hh[colg]
__global__ void prep_tbl(const float* __restrict__ E, const float* __restrict__ W_ih,
                         const float* __restrict__ b_ih, const float* __restrict__ b_hh,
                         unsigned short* __restrict__ tbl) {
  int tid = blockIdx.x * 256 + threadIdx.x;
  if (tid >= VOCAB * G4) return;
  int v = tid / G4, col = tid % G4;
  float s = b_ih[col] + b_hh[col];
  if (v != 0) {
    const float* Er = E + v * EMB;
    const float* Wr = W_ih + col * EMB;
    for (int e = 0; e < EMB; ++e) s += Er[e] * Wr[e];
  }
  tbl[tid] = f2bf(s);
}

// ---------------- prep 2: pack Wp as the MFMA *A*-operand ----------------
// A-frag order: lane l elem i = A[rr = l&15][k = 32s+8*(l>>4)+i].
// Gate tiles n<50: rr = 4*jj + g -> gate g of hidden j = 4n+jj;
//   gate-major col colg = g*200 + j.
//   A[rr][k] = W_hh[colg*HID+k] (k<200) | tbl[k-201][colg] (201<=k<219) | 0.
// Logit tiles n=50,51: rr = vocab v - 16*(n-50):
//   A[rr][k] = W_out[v*HID+k] (k<200) | b_out[v] (k==200) | 0.
__global__ void prep_wp(const float* __restrict__ W_hh, const float* __restrict__ W_out,
                        const float* __restrict__ b_out,
                        const unsigned short* __restrict__ tbl,
                        short* __restrict__ Wp) {
  int u = blockIdx.x * 256 + threadIdx.x;
  if (u >= NT * KS * 64) return;
  int n    = u / (KS * 64);
  int rem  = u % (KS * 64);
  int s_   = rem >> 6;
  int lane = rem & 63;
  int rr   = lane & 15;
  int kb   = lane >> 4;
  s16x8 o;
  #pragma unroll
  for (int i = 0; i < 8; ++i) {
    int k = 32 * s_ + 8 * kb + i;
    short b = 0;
    if (n < 50) {
      int g = rr & 3, j = 4 * n + (rr >> 2);
      int colg = g * 200 + j;
      if (k < HID)                          b = (short)f2bf(W_hh[colg * HID + k]);
      else if (k >= 201 && k < 201 + VOCAB) b = (short)tbl[(k - 201) * G4 + colg];
    } else if (n < 52) {
      int v = 16 * (n - 50) + rr;
      if (v < VOCAB) {
        if (k < HID)       b = (short)f2bf(W_out[v * HID + k]);
        else if (k == HID) b = (short)f2bf(b_out[v]);
      }
    }
    o[i] = b;
  }
  *(s16x8*)(Wp + (size_t)u * 8) = o;
}

// ---------------- main ----------------
// OPERAND-SWAPPED: D = W_tile(A) x h(B). C layout: lane col = batch (l&15,
// 0..7 valid), regs q = the 4 gates of hidden j = 4n + (l>>4) -> NO transpose,
// NO cross-lane ops. One-hot token rows live in hA memory (R7 scheme).
// EW runs twice per pair on the 32 valid lanes. 392 pinned weight AGPRs/wave.
__global__ __launch_bounds__(TPB) __attribute__((amdgpu_waves_per_eu(1, 1)))
void lstm_kernel(const int* __restrict__ x, const short* __restrict__ Wp,
                 float* __restrict__ out) {
  __shared__ unsigned short hA[KS * 64 * 8];   // h as B-frag layout bf16 (7.2KB)
  __shared__ int   xtok[MB * SEQ];             // 4KB
  __shared__ float logL[MB * SV];              // logits buffer (73.7KB)

  const int tid  = threadIdx.x;
  const int lane = tid & 63;
  const int w    = tid >> 6;                   // wave 0..3
  const int blk  = blockIdx.x;
  const int jw   = 56 * w;                     // wave's j base
  const bool hi8 = lane & 8;                   // C col >= 8 (padding cols)
  const int c8   = lane & 7;                   // batch row (valid lanes)
  const int kb   = lane >> 4;                  // reg-quadrant -> jj within tile

  // h0 = 0; bf16 1.0 at bias slot k=200, cols 0..7 (elems 3200+8c)
  for (int i = tid; i < KS * 64 * 8; i += TPB)
    hA[i] = (i >= 3200 && i < 3264 && (i & 7) == 0) ? (unsigned short)0x3F80
                                                    : (unsigned short)0;
  for (int i = tid; i < MB * SEQ; i += TPB) xtok[i] = x[blk * (MB * SEQ) + i];

  // weight fragments: 14 tiles x 7 steps x 4 regs = 392 AGPRs, pinned once.
  s16x8 wf[TPW][KS];
  #pragma unroll
  for (int n = 0; n < TPW; ++n) {
    #pragma unroll
    for (int s = 0; s < KS; ++s) {
      wf[n][s] = *(const s16x8*)(Wp + ((((w * TPW + n) * KS) + s) * 64 + lane) * 8);
      asm volatile("" : "+a"(wf[n][s]));
    }
    asm volatile("" ::: "memory");
  }

  __syncthreads();
  // one-hot for t=0 in hA memory (after barrier: zero-init complete)
  if (tid < MB) hA[oh_elem(tid, 201 + xtok[tid * SEQ])] = 0x3F80;

  float ccA[7] = {0, 0, 0, 0, 0, 0, 0};        // c state, tile 2P   (lane c8, j=8P+kb)
  float ccB[7] = {0, 0, 0, 0, 0, 0, 0};        // c state, tile 2P+1 (j=8P+4+kb)
  const f32x4 zz = {0.f, 0.f, 0.f, 0.f};
  __syncthreads();

#define MFMA_PAIR(nt, A, B) {                                                   \
    _Pragma("unroll")                                                           \
    for (int s = 0; s < KS; ++s) {                                              \
      A = __builtin_amdgcn_mfma_f32_16x16x32_bf16(wf[nt][s],     aF[s], A, 0,0,0); \
      B = __builtin_amdgcn_mfma_f32_16x16x32_bf16(wf[(nt)+1][s], aF[s], B, 0,0,0); \
    } }

#define EW_ONE(V, CC, J) {                                                      \
    float i_ = sigm(V[0]), f_ = sigm(V[1]), g_ = tanhq(V[2]), o_ = sigm(V[3]);  \
    float cn = f_ * (CC) + i_ * g_;                                             \
    float h  = o_ * tanhq(cn);                                                  \
    (CC) = cn;                                                                  \
    hA[(((J) >> 5) * 64 + 16 * (((J) >> 3) & 3) + c8) * 8 + ((J) & 7)] = f2bf(h); \
    if (t == SEQ - 1) {                                                         \
      size_t bg = (size_t)blk * MB + c8;                                        \
      out[LOGITS_N + bg * HID + (J)] = h;                                       \
      out[LOGITS_N + (size_t)BATCH * HID + bg * HID + (J)] = cn;                \
    } }

#define EW_PAIR(P, A, B)                                                        \
    if (!hi8) {                                                                 \
      int J0 = jw + 8 * (P) + kb;                                               \
      EW_ONE(A, ccA[P], J0);                                                    \
      EW_ONE(B, ccB[P], J0 + 4);                                                \
    }

// logit tiles: lane col = batch c (l&15 < 8 valid), regs q -> v = 4*kb+q.
#define LOGIT_STORE(TT, A, B)                                                   \
    if (!hi8) {                                                                 \
      int vg = 4 * kb;                                                          \
      _Pragma("unroll")                                                         \
      for (int q = 0; q < 4; ++q) {                                             \
        logL[c8 * SV + (TT) * VOCAB + vg + q] = A[q];                           \
        if (vg + q < 2) logL[c8 * SV + (TT) * VOCAB + 16 + vg + q] = B[q];      \
      } }

  #pragma unroll 1
  for (int t = 0; t < SEQ; ++t) {
    // ---- load h (+bias row, +one-hot rows) as B fragments ----
    s16x8 aF[KS];
    #pragma unroll
    for (int s = 0; s < KS; ++s) aF[s] = *(const s16x8*)&hA[(s * 64 + lane) * 8];
    __syncthreads();   // all waves hold h_t before anyone writes h_{t+1}

    if (w < 3) {       // 7 gate pairs, 2-stage software pipeline
      f32x4 A0 = zz, B0 = zz, A1 = zz, B1 = zz;
      MFMA_PAIR(0, A0, B0);
      MFMA_PAIR(2, A1, B1);   EW_PAIR(0, A0, B0);
      A0 = zz; B0 = zz;
      MFMA_PAIR(4, A0, B0);   EW_PAIR(1, A1, B1);
      A1 = zz; B1 = zz;
      MFMA_PAIR(6, A1, B1);   EW_PAIR(2, A0, B0);
      A0 = zz; B0 = zz;
      MFMA_PAIR(8, A0, B0);   EW_PAIR(3, A1, B1);
      A1 = zz; B1 = zz;
      MFMA_PAIR(10, A1, B1);  EW_PAIR(4, A0, B0);
      A0 = zz; B0 = zz;
      MFMA_PAIR(12, A0, B0);  EW_PAIR(5, A1, B1);
      EW_PAIR(6, A0, B0);
    } else {           // 4 gate pairs (tiles 42-49) + logit pair (local 8,9)
      f32x4 A0 = zz, B0 = zz, A1 = zz, B1 = zz;
      MFMA_PAIR(0, A0, B0);
      MFMA_PAIR(2, A1, B1);   EW_PAIR(0, A0, B0);
      A0 = zz; B0 = zz;
      MFMA_PAIR(4, A0, B0);   EW_PAIR(1, A1, B1);
      A1 = zz; B1 = zz;
      MFMA_PAIR(6, A1, B1);   EW_PAIR(2, A0, B0);
      A0 = zz; B0 = zz;
      MFMA_PAIR(8, A0, B0);   EW_PAIR(3, A1, B1);   // logit MFMAs
      if (t > 0) LOGIT_STORE(t - 1, A0, B0);
    }
    // one-hot advance in hA: clear x[t], set x[t+1] (same thread -> ordered;
    // disjoint from all h-writes: k>=201 slots vs k<200 slots)
    if (tid < MB && t + 1 < SEQ) {
      int v0 = xtok[tid * SEQ + t];
      int v1 = xtok[tid * SEQ + t + 1];
      hA[oh_elem(tid, 201 + v0)] = 0;
      hA[oh_elem(tid, 201 + v1)] = 0x3F80;
    }
    __syncthreads();
  }

  // ---- epilogue: logits for t=SEQ-1 from final h (stale one-hot rows hit
  // zeroed A-cols of the logit tiles, harmless) ----
  if (w == 3) {
    s16x8 aF[KS];
    #pragma unroll
    for (int s = 0; s < KS; ++s) aF[s] = *(const s16x8*)&hA[(s * 64 + lane) * 8];
    f32x4 A0 = zz, B0 = zz;
    MFMA_PAIR(8, A0, B0);
    LOGIT_STORE(SEQ - 1, A0, B0);
  }
  __syncthreads();

  // ---- flush logits: block's region is contiguous [blk*8 rows][128][18] ----
  float* dst = out + (size_t)blk * (MB * SV);
  for (int i = tid * 4; i < MB * SV; i += TPB * 4)
    *(f32x4*)&dst[i] = *(const f32x4*)&logL[i];

#undef MFMA_PAIR
#undef EW_ONE
#undef EW_PAIR
#undef LOGIT_STORE
}

extern "C" void kernel_launch(void* const* d_in, const int* in_sizes, int n_in,
                              void* d_out, int out_size, void* d_ws, size_t ws_size,
                              hipStream_t stream) {
  const int*   x     = (const int*)  d_in[0];
  const float* E     = (const float*)d_in[1];
  const float* W_ih  = (const float*)d_in[2];
  const float* W_hh  = (const float*)d_in[3];
  const float* b_ih  = (const float*)d_in[4];
  const float* b_hh  = (const float*)d_in[5];
  const float* W_out = (const float*)d_in[6];
  const float* b_out = (const float*)d_in[7];
  float* out = (float*)d_out;

  // ws layout: tbl 18*800*2 = 28800B | Wp 56*7*64*8*2 = 401408B   (~430KB)
  unsigned short* tbl = (unsigned short*)d_ws;
  short* Wp = (short*)d_ws + VOCAB * G4;

  prep_tbl<<<(VOCAB * G4 + 255) / 256, 256, 0, stream>>>(E, W_ih, b_ih, b_hh, tbl);
  prep_wp<<<(NT * KS * 64 + 255) / 256, 256, 0, stream>>>(W_hh, W_out, b_out, tbl, Wp);
  lstm_kernel<<<BATCH / MB, TPB, 0, stream>>>(x, Wp, out);
}